// Round 3
// baseline (436.545 us; speedup 1.0000x reference)
//
#include <hip/hip_runtime.h>

typedef _Float16 half8    __attribute__((ext_vector_type(8)));
typedef float    floatx16 __attribute__((ext_vector_type(16)));
typedef float    float4v  __attribute__((ext_vector_type(4)));

#define K_DIM 256
#define N_DIM 256

// Build W^T in f16 bit patterns: W[k][n] = 2^shift[k][n] * (-1)^sign[k][n].
// shift is an exact integer in [-10,-1]; 2^shift is exact in f16.
__global__ __launch_bounds__(256) void build_wT(const float* __restrict__ shift,
                                                const float* __restrict__ sgn,
                                                unsigned short* __restrict__ wT) {
    int idx = blockIdx.x * 256 + threadIdx.x;   // idx = k*256 + n
    int k = idx >> 8, n = idx & 255;
    float sh = shift[idx];
    float sg = sgn[idx];
    int e = 15 + (int)sh;                       // f16 exponent field, 5..14
    unsigned short wv = (unsigned short)(((sg != 0.0f) ? 0x8000 : 0) | (e << 10));
    wT[n * 256 + k] = wv;                       // W^T[n][k], contiguous K
}

// Barrier-free, LDS-free streaming GEMM. One wave = 32 rows x 256 cols.
// A fragments loaded straight from global (f32 -> f16 in-register);
// B fragments loaded from the L1/L2-resident 128 KB W^T.
__global__ __launch_bounds__(256, 2) void dense_shift_gemm(
        const float* __restrict__ x,
        const unsigned short* __restrict__ wT,
        const float* __restrict__ bias,
        float* __restrict__ out) {

    const int t  = threadIdx.x;
    const int l  = t & 63;
    const int ln = l & 31;
    const int hi = l >> 5;

    const long gw   = (long)blockIdx.x * 4 + (t >> 6);   // global wave id, 0..16383
    const long row0 = gw * 32;

    // A-fragment pointer (mfma_f32_32x32x16_f16 A layout: row = l&31, k = (l>>5)*8 + j):
    // lane reads 8 consecutive f32 of its row; lanes l and l+32 share 64-B lines.
    const float* ax = x + (row0 + ln) * (long)K_DIM + hi * 8;

    // B-fragment pointer (B layout: col = l&31, k = (l>>5)*8 + j); W^T[n][k] contiguous in k.
    const unsigned short* bx = wT + ln * K_DIM + hi * 8;

    // Hoist bias (L2-hot) so the epilogue has no load latency.
    float bv[8];
#pragma unroll
    for (int nb = 0; nb < 8; ++nb) bv[nb] = bias[nb * 32 + ln];

    floatx16 acc[8];
#pragma unroll
    for (int nb = 0; nb < 8; ++nb)
#pragma unroll
        for (int r = 0; r < 16; ++r) acc[nb][r] = 0.0f;

    // Fully-unrolled K loop: compiler is free to hoist A-loads arbitrarily early
    // (no barriers in the way) and keep several HBM loads in flight per wave.
#pragma unroll
    for (int ks = 0; ks < 16; ++ks) {
        float4v f0 = *(const float4v*)(ax + ks * 16);
        float4v f1 = *(const float4v*)(ax + ks * 16 + 4);
        half8 a;
        a[0] = (_Float16)f0[0]; a[1] = (_Float16)f0[1];
        a[2] = (_Float16)f0[2]; a[3] = (_Float16)f0[3];
        a[4] = (_Float16)f1[0]; a[5] = (_Float16)f1[1];
        a[6] = (_Float16)f1[2]; a[7] = (_Float16)f1[3];
#pragma unroll
        for (int nb = 0; nb < 8; ++nb) {
            half8 b = *(const half8*)(bx + nb * 32 * K_DIM + ks * 16);
            acc[nb] = __builtin_amdgcn_mfma_f32_32x32x16_f16(a, b, acc[nb], 0, 0, 0);
        }
    }

    // Epilogue: bias + store. C layout: col = l&31, row = (r&3) + 8*(r>>2) + 4*(l>>5).
    // Each store instruction covers 2 rows x 128 B contiguous — coalesced.
    float* op = out + (row0 + 4 * hi) * (long)N_DIM + ln;
#pragma unroll
    for (int nb = 0; nb < 8; ++nb) {
#pragma unroll
        for (int r = 0; r < 16; ++r) {
            const int row = (r & 3) + 8 * (r >> 2);
            op[(long)row * N_DIM + nb * 32] = acc[nb][r] + bv[nb];
        }
    }
}

extern "C" void kernel_launch(void* const* d_in, const int* in_sizes, int n_in,
                              void* d_out, int out_size, void* d_ws, size_t ws_size,
                              hipStream_t stream) {
    const float* x     = (const float*)d_in[0];
    const float* shift = (const float*)d_in[1];
    const float* sgn   = (const float*)d_in[2];
    const float* bias  = (const float*)d_in[3];
    float* out = (float*)d_out;
    unsigned short* wT = (unsigned short*)d_ws;   // 256*256*2 = 128 KB scratch

    build_wT<<<256, 256, 0, stream>>>(shift, sgn, wT);

    // 16384 waves of 32 rows each = 524288 rows; 4 waves/block -> 4096 blocks.
    dense_shift_gemm<<<4096, 256, 0, stream>>>(x, wT, bias, out);
}

// Round 4
// 219.208 us; speedup vs baseline: 1.9915x; 1.9915x over previous
//
#include <hip/hip_runtime.h>

typedef _Float16 half8    __attribute__((ext_vector_type(8)));
typedef float    floatx16 __attribute__((ext_vector_type(16)));
typedef float    float4v  __attribute__((ext_vector_type(4)));

#define K_DIM 256
#define N_DIM 256

typedef const __attribute__((address_space(1))) void global_cv_t;
typedef __attribute__((address_space(3))) void lds_v_t;

// Build W^T in f16 bit patterns: W[k][n] = 2^shift[k][n] * (-1)^sign[k][n].
// shift is an exact integer in [-10,-1]; 2^shift is exact in f16.
__global__ __launch_bounds__(256) void build_wT(const float* __restrict__ shift,
                                                const float* __restrict__ sgn,
                                                unsigned short* __restrict__ wT) {
    int idx = blockIdx.x * 256 + threadIdx.x;   // idx = k*256 + n
    int k = idx >> 8, n = idx & 255;
    float sh = shift[idx];
    float sg = sgn[idx];
    int e = 15 + (int)sh;                       // f16 exponent field, 5..14
    unsigned short wv = (unsigned short)(((sg != 0.0f) ? 0x8000 : 0) | (e << 10));
    wT[n * 256 + k] = wv;                       // W^T[n][k], contiguous K
}

// One barrier total. B (W^T) lives in LDS (lgkmcnt domain); A streams through
// double-buffered REGISTERS in strict issue order (vmcnt FIFO works naturally).
__global__ __launch_bounds__(512, 2) void dense_shift_gemm(
        const float* __restrict__ x,
        const unsigned short* __restrict__ wT,
        const float* __restrict__ bias,
        float* __restrict__ out) {

    // Full W^T in LDS, f16, XOR-swizzled: bLds[n][s] holds W^T[n][(s^(n&31))*8 .. +8]
    // (s = 16-byte slot, 32 slots per 512-B row). Read side XORs the same way ->
    // lanes 0..31 (consecutive n, same k-slot) hit 32 distinct slots: conflict-free.
    __shared__ __align__(16) unsigned short bLds[256 * 256];   // 128 KB

    const int t  = threadIdx.x;
    const int w  = t >> 6;            // wave 0..7
    const int l  = t & 63;
    const int ln = l & 31;
    const int hi = l >> 5;

    const long gw   = (long)blockIdx.x * 8 + w;   // global wave id
    const long row0 = gw * 32;                    // this wave's 32 output rows

    // ---- B init: per-wave DMA, 32 W^T rows per wave, source-swizzled ----
    {
        const int rr = l >> 5;        // row within pair
        const int sl = l & 31;        // dest slot
#pragma unroll
        for (int i = 0; i < 16; ++i) {
            const int n  = w * 32 + i * 2 + rr;
            const int sw = sl ^ (n & 31);                       // involution
            const unsigned short* g = wT + n * 256 + sw * 8;
            __builtin_amdgcn_global_load_lds(
                (global_cv_t*)g,
                (lds_v_t*)((char*)bLds + (w * 32 + i * 2) * 512),
                16, 0, 0);
        }
    }

    // ---- A chunk 0 into registers (start HBM early; drained by the barrier) ----
    const float* ax = x + (row0 + ln) * (long)K_DIM + hi * 8;
    float4v A0[8], A1[8];
#pragma unroll
    for (int ks = 0; ks < 4; ++ks) {
        A0[2 * ks]     = *(const float4v*)(ax + ks * 16);
        A0[2 * ks + 1] = *(const float4v*)(ax + ks * 16 + 4);
    }

    float bv[8];
#pragma unroll
    for (int nb = 0; nb < 8; ++nb) bv[nb] = bias[nb * 32 + ln];

    __syncthreads();   // the ONLY barrier: B-LDS ready

    floatx16 acc[8];
#pragma unroll
    for (int nb = 0; nb < 8; ++nb)
#pragma unroll
        for (int r = 0; r < 16; ++r) acc[nb][r] = 0.0f;

    const char* bl = (const char*)bLds;

    // Load chunk kc into register set R_ (8 x dwordx4 = 8 KB/wave in flight),
    // pinned ahead of the following compute by sched_barrier(0).
#define LOADR(R_, kc_) do {                                                   \
        _Pragma("unroll")                                                     \
        for (int ks = 0; ks < 4; ++ks) {                                      \
            R_[2 * ks]     = *(const float4v*)(ax + (kc_) * 64 + ks * 16);    \
            R_[2 * ks + 1] = *(const float4v*)(ax + (kc_) * 64 + ks * 16 + 4);\
        }                                                                     \
        __builtin_amdgcn_sched_barrier(0);                                    \
    } while (0)

    // Compute one K=64 chunk from register set R_: cvt f32->f16, B from LDS.
#define COMPUTE(R_, kc_) do {                                                 \
        _Pragma("unroll")                                                     \
        for (int ks = 0; ks < 4; ++ks) {                                      \
            float4v f0 = R_[2 * ks], f1 = R_[2 * ks + 1];                     \
            half8 a;                                                          \
            a[0] = (_Float16)f0[0]; a[1] = (_Float16)f0[1];                   \
            a[2] = (_Float16)f0[2]; a[3] = (_Float16)f0[3];                   \
            a[4] = (_Float16)f1[0]; a[5] = (_Float16)f1[1];                   \
            a[6] = (_Float16)f1[2]; a[7] = (_Float16)f1[3];                   \
            _Pragma("unroll")                                                 \
            for (int nb = 0; nb < 8; ++nb) {                                  \
                const int g_ = (kc_) * 8 + ks * 2 + hi;                       \
                const half8* bq = (const half8*)(bl + (size_t)nb * 16384      \
                                   + (size_t)ln * 512 + (((g_) ^ ln) << 4));  \
                half8 b = *bq;                                                \
                acc[nb] = __builtin_amdgcn_mfma_f32_32x32x16_f16(a, b, acc[nb], 0, 0, 0); \
            }                                                                 \
        }                                                                     \
    } while (0)

    // ---- barrier-free K pipeline: next chunk's loads always in flight ----
    LOADR(A1, 1);
    COMPUTE(A0, 0);
    LOADR(A0, 2);
    COMPUTE(A1, 1);
    LOADR(A1, 3);
    COMPUTE(A0, 2);
    COMPUTE(A1, 3);

#undef LOADR
#undef COMPUTE

    // ---- epilogue: bias + store (fire-and-forget; kernel end drains) ----
    // C layout: col = l&31, row = (r&3) + 8*(r>>2) + 4*(l>>5).
    float* op = out + (row0 + 4 * hi) * (long)N_DIM + ln;
#pragma unroll
    for (int nb = 0; nb < 8; ++nb) {
#pragma unroll
        for (int r = 0; r < 16; ++r) {
            const int row = (r & 3) + 8 * (r >> 2);
            op[(long)row * N_DIM + nb * 32] = acc[nb][r] + bv[nb];
        }
    }
}

extern "C" void kernel_launch(void* const* d_in, const int* in_sizes, int n_in,
                              void* d_out, int out_size, void* d_ws, size_t ws_size,
                              hipStream_t stream) {
    const float* x     = (const float*)d_in[0];
    const float* shift = (const float*)d_in[1];
    const float* sgn   = (const float*)d_in[2];
    const float* bias  = (const float*)d_in[3];
    float* out = (float*)d_out;
    unsigned short* wT = (unsigned short*)d_ws;   // 256*256*2 = 128 KB scratch

    build_wT<<<256, 256, 0, stream>>>(shift, sgn, wT);

    // 2048 blocks x 8 waves x 32 rows = 524288 rows.
    dense_shift_gemm<<<2048, 512, 0, stream>>>(x, wT, bias, out);
}